// Round 9
// baseline (71.248 us; speedup 1.0000x reference)
//
#include <hip/hip_runtime.h>

#define BB 64
#define NN 64
#define TT 100
#define TQ 4                  // consecutive t's per block
#define NTQ (TT / TQ)         // 25 t-chunks

// Kernel 1: block = (n, t0..t0+3) tile, 256 threads / 4 waves (R6/R8 structure).
// Inner loop: min-only difference-form d2; self excluded by the uint trick
// (self d2 is bit-exact +0.0 -> float_bits-1 wraps to UINT_MAX, dropped by
// v_min_u32; +1 after reduction restores exact float bits) — removes the
// per-c cmp+cndmask. S read as float4 pairs via wave-uniform ds_read_b128.
__global__ __launch_bounds__(256) void social_slice_kernel(
    const float* __restrict__ x,          // (B, N, T, 6) f32
    const float* __restrict__ wfa,        // (B, 3, 3)    f32
    const int* __restrict__ rand_idx,     // (T*N, B)     i32 in [0, B-2]
    const int* __restrict__ drop_mask,    // (T*N, B)     bool stored as i32
    float* __restrict__ ws)               // (NTQ, NN, BB) 4-t partial sums
{
    const int n  = blockIdx.x & 63;       // grid = NTQ*64 blocks
    const int tq = blockIdx.x >> 6;       // 0..24
    const int t0 = tq * TQ;

    __shared__ float2 S[TQ][BB + 2];      // +2: row = 528 B, float4-aligned
    __shared__ float  Rld[TQ][BB];

    // ---- phase 1: coalesced load + transform ----
    {
        const int lb = threadIdx.x >> 2;  // 0..63
        const int k  = threadIdx.x & 3;   // 0..3
        const float* wp = wfa + lb * 9;
        const float r00 = wp[0], r01 = wp[1], tx = wp[2];
        const float r10 = wp[3], r11 = wp[4], ty = wp[5];
        const size_t xoff = (((size_t)lb * NN + n) * (size_t)TT + (size_t)(t0 + k)) * 6;
        const float2 p = *(const float2*)(x + xoff);   // even offset -> 8B aligned
        const float gx = r00 * p.x + r01 * p.y + tx;
        const float gy = r10 * p.x + r11 * p.y + ty;
        S[k][lb] = make_float2(gx, gy);
    }
    __syncthreads();

    // ---- phase 2: wave w handles slice t = t0 + w ----
    const int w = threadIdx.x >> 6;
    const int b = threadIdx.x & 63;
    const int t = t0 + w;
    const int s = t * NN + n;
    const size_t sb = (size_t)s * BB + b;
    const int r  = rand_idx[sb];          // coalesced, issued early
    const int dm = drop_mask[sb];

    const float2 g = S[w][b];
    const float gx = g.x, gy = g.y;

    // min over c != b of (gx-qx)^2 + (gy-qy)^2, in uint domain.
    // 4 chains x 16 c's, 2 c's per ds_read_b128 (c even -> 16B aligned).
    unsigned m0 = 0xFFFFFFFFu, m1 = 0xFFFFFFFFu, m2 = 0xFFFFFFFFu, m3 = 0xFFFFFFFFu;
    #pragma unroll
    for (int i = 0; i < 8; ++i) {
        {
            const int c = 2 * i;
            const float4 q = *(const float4*)&S[w][c];   // wave-uniform -> broadcast
            const float dx0 = gx - q.x, dy0 = gy - q.y;
            const float dx1 = gx - q.z, dy1 = gy - q.w;
            const unsigned u0 = __float_as_uint(fmaf(dx0, dx0, dy0 * dy0)) - 1u;
            const unsigned u1 = __float_as_uint(fmaf(dx1, dx1, dy1 * dy1)) - 1u;
            m0 = min(m0, min(u0, u1));
        }
        {
            const int c = 16 + 2 * i;
            const float4 q = *(const float4*)&S[w][c];
            const float dx0 = gx - q.x, dy0 = gy - q.y;
            const float dx1 = gx - q.z, dy1 = gy - q.w;
            const unsigned u0 = __float_as_uint(fmaf(dx0, dx0, dy0 * dy0)) - 1u;
            const unsigned u1 = __float_as_uint(fmaf(dx1, dx1, dy1 * dy1)) - 1u;
            m1 = min(m1, min(u0, u1));
        }
        {
            const int c = 32 + 2 * i;
            const float4 q = *(const float4*)&S[w][c];
            const float dx0 = gx - q.x, dy0 = gy - q.y;
            const float dx1 = gx - q.z, dy1 = gy - q.w;
            const unsigned u0 = __float_as_uint(fmaf(dx0, dx0, dy0 * dy0)) - 1u;
            const unsigned u1 = __float_as_uint(fmaf(dx1, dx1, dy1 * dy1)) - 1u;
            m2 = min(m2, min(u0, u1));
        }
        {
            const int c = 48 + 2 * i;
            const float4 q = *(const float4*)&S[w][c];
            const float dx0 = gx - q.x, dy0 = gy - q.y;
            const float dx1 = gx - q.z, dy1 = gy - q.w;
            const unsigned u0 = __float_as_uint(fmaf(dx0, dx0, dy0 * dy0)) - 1u;
            const unsigned u1 = __float_as_uint(fmaf(dx1, dx1, dy1 * dy1)) - 1u;
            m3 = min(m3, min(u0, u1));
        }
    }
    const unsigned mu = min(min(m0, m1), min(m2, m3));
    const float best = __uint_as_float(mu + 1u);   // exact min d2 over c != b

    // drop-lane neighbor distance: reference sq-form via shfl (exact ref path)
    const int rnb = r + (r >= b ? 1 : 0); // skip-self remap, never == b
    const float sq  = fmaf(gx, gx, gy * gy);
    const float qx  = __shfl(gx, rnb);
    const float qy  = __shfl(gy, rnb);
    const float qsq = __shfl(sq, rnb);
    const float d2r = fmaf(-2.0f, fmaf(gx, qx, gy * qy), sq + qsq);

    const float d2sel = dm ? d2r : best;
    const float nd = sqrtf(fmaxf(d2sel, 1e-12f));
    const float diff = nd - 1.5f;
    Rld[w][b] = diff * diff;
    __syncthreads();

    // ---- phase 3: combine the block's 4 t's, one coalesced 256 B store ----
    if (w == 0) {
        const float sum4 = ((Rld[0][b] + Rld[1][b]) + Rld[2][b]) + Rld[3][b];
        ws[((size_t)tq * NN + n) * BB + b] = sum4;
    }
}

// Kernel 2: out[b,n] = (1/T) * sum_tq ws[tq][n][b].
// 64 blocks (one per n) x 256 threads; wave w sums tq = w, w+4, ... (<=7 loads),
// LDS-combines the 4 wave partials.
__global__ __launch_bounds__(256) void social_reduce_kernel(
    const float* __restrict__ ws,
    float* __restrict__ out)              // (B, N)
{
    const int n = blockIdx.x;
    const int w = threadIdx.x >> 6;
    const int b = threadIdx.x & 63;

    float acc = 0.f;
    #pragma unroll
    for (int tq = w; tq < NTQ; tq += 4)
        acc += ws[((size_t)tq * NN + n) * BB + b];

    __shared__ float R2[4][BB];
    R2[w][b] = acc;
    __syncthreads();
    if (w == 0)
        out[b * NN + n] = (((R2[0][b] + R2[1][b]) + R2[2][b]) + R2[3][b]) * (1.0f / TT);
}

extern "C" void kernel_launch(void* const* d_in, const int* in_sizes, int n_in,
                              void* d_out, int out_size, void* d_ws, size_t ws_size,
                              hipStream_t stream) {
    const float* x = (const float*)d_in[0];
    const float* wfa = (const float*)d_in[1];
    const int* rand_idx = (const int*)d_in[2];
    const int* drop_mask = (const int*)d_in[3];
    float* out = (float*)d_out;
    float* ws = (float*)d_ws;             // needs 25*64*64*4 = 400 KB

    social_slice_kernel<<<NTQ * NN, 256, 0, stream>>>(
        x, wfa, rand_idx, drop_mask, ws);
    social_reduce_kernel<<<NN, 256, 0, stream>>>(ws, out);
}